// Round 8
// baseline (1153.584 us; speedup 1.0000x reference)
//
#include <hip/hip_runtime.h>
#include <cstdint>

// EncoderLayer_52192442581853 — MI355X (gfx950)
// Dtype model: inputs/weights/output are ALL f32 on device. Internal compute:
// bf16 MFMA with f32 accumulation (threshold = 2% * max|ref| = 0.1175).
//
// Round 14 = Round 13 with the pgh RACE FIXED: G34's per-(row,tile) LN
// partials were indexed without the head -> all 8 heads overwrote the same
// slots -> wrong g/h stats (absmax 1.47). pgh is now [R][8h][7t][2wn][2] and
// ln_stats_gh reduces across heads.
//
// Structure (from R13): both standalone LN kernels eliminated:
//  - G12/G34 epilogues emit partial (sum,sumsq); tiny stats kernels reduce to
//    per-row (mean,rstd) in lrms/ghms.
//  - G34 A-stage LNs cs_chunk on the fly (lcg/rcg); G5 A-stage LN+relu on
//    h_pre; G5 epilogue LN+sigmoid gates + lci/rci from cs_chunk.
//
// Pipeline:
//   P0:  WT_* = bf16(W_*^T)
//   RS:  Srow_p 64-row sums; in_bf16 = bf16(inputs)
//   CS:  colsum_p = Srow_p @ W_csum + 64*b  (EPI=4)
//   S1:  offs[128][4096] = exclusive scan
//   per chunk:  G12 (cumsum+outx+cs partials) -> stats_cs ->
//               G34 (LN-A-stage, g/h raw + partials) -> stats_gh ->
//               G5 (LN(h)relu A-stage, gating epilogue) -> G6 (out + resid)

typedef __bf16 bf16_t;
using bf16x8 = __attribute__((ext_vector_type(8))) __bf16;
using bf16x4 = __attribute__((ext_vector_type(4))) __bf16;
using f32x4  = __attribute__((ext_vector_type(4))) float;

#define EPSF 1e-6f

// ---------------- weight transpose: f32 [K][N] -> bf16 [N][K] ----------------
__global__ __launch_bounds__(256) void wtrans_kernel(
    const float* __restrict__ W, bf16_t* __restrict__ WT, int K, int N,
    long outSliceStride) {
  __shared__ float tile[64][65];
  const long slice = (long)K * N;
  const float* Wp = W + (long)blockIdx.z * slice;
  bf16_t* Tp = WT + (long)blockIdx.z * outSliceStride;
  const int n0 = blockIdx.x * 64, k0 = blockIdx.y * 64;
  const int c = threadIdx.x & 63, r0 = threadIdx.x >> 6;
#pragma unroll
  for (int i = 0; i < 16; ++i)
    tile[i * 4 + r0][c] = Wp[(long)(k0 + i * 4 + r0) * N + (n0 + c)];
  __syncthreads();
#pragma unroll
  for (int i = 0; i < 16; ++i)
    Tp[(long)(n0 + i * 4 + r0) * K + (k0 + c)] = (bf16_t)tile[c][i * 4 + r0];
}

// -------- rowsum + cvt: Srow_p[sub*2+half][k] = sum over 64 rows; inb = bf16(in) --------
__global__ __launch_bounds__(256) void rowsum_cvt_kernel(
    const float* __restrict__ in, float* __restrict__ S, bf16_t* __restrict__ ob) {
  const int k = threadIdx.x * 4;
  const int half = blockIdx.x;
  const int sub = blockIdx.y;
  const long rbase = (long)sub * 128 + (long)half * 64;
  const float* p = in + rbase * 1024 + k;
  bf16_t* q = ob + rbase * 1024 + k;
  f32x4 s = {0.f, 0.f, 0.f, 0.f};
#pragma unroll 4
  for (int r = 0; r < 64; ++r) {
    const f32x4 v = *(const f32x4*)(p + (long)r * 1024);
    s += v;
    bf16x4 o;
#pragma unroll
    for (int j = 0; j < 4; ++j) o[j] = (bf16_t)v[j];
    *(bf16x4*)(q + (long)r * 1024) = o;
  }
  *(f32x4*)(S + ((long)sub * 2 + half) * 1024 + k) = s;
}

// -------- stats: reduce partials -> per-row (mean, rstd) pairs --------
__global__ __launch_bounds__(256) void ln_stats_cs_kernel(
    const float* __restrict__ pcs, float* __restrict__ lrms, int Rtot) {
  const int r = blockIdx.x * 256 + threadIdx.x;
  if (r >= Rtot) return;
  const float* p = pcs + (long)r * 128;  // [32 tiles][2 wn][2]
  float s = 0.f, s2 = 0.f;
#pragma unroll
  for (int t = 0; t < 16; ++t) { s += p[t*4] + p[t*4+2]; s2 += p[t*4+1] + p[t*4+3]; }
  float mean = s * (1.f / 2048.f);
  lrms[r*4+0] = mean;
  lrms[r*4+1] = rsqrtf(s2 * (1.f / 2048.f) - mean * mean + EPSF);
  s = 0.f; s2 = 0.f;
#pragma unroll
  for (int t = 16; t < 32; ++t) { s += p[t*4] + p[t*4+2]; s2 += p[t*4+1] + p[t*4+3]; }
  mean = s * (1.f / 2048.f);
  lrms[r*4+2] = mean;
  lrms[r*4+3] = rsqrtf(s2 * (1.f / 2048.f) - mean * mean + EPSF);
}

__global__ __launch_bounds__(256) void ln_stats_gh_kernel(
    const float* __restrict__ pgh, float* __restrict__ ghms, int Rtot) {
  const int r = blockIdx.x * 256 + threadIdx.x;
  if (r >= Rtot) return;
  const float* p = pgh + (long)r * 224;  // [8 h][7 tiles][2 wn][2]
  float s = 0.f, s2 = 0.f;
#pragma unroll
  for (int hh = 0; hh < 8; ++hh)
#pragma unroll
    for (int t = 0; t < 3; ++t) {
      const int b = (hh * 7 + t) * 4;
      s += p[b] + p[b + 2]; s2 += p[b + 1] + p[b + 3];
    }
  float mean = s * (1.f / 3072.f);
  ghms[r*4+0] = mean;
  ghms[r*4+1] = rsqrtf(s2 * (1.f / 3072.f) - mean * mean + EPSF);
  s = 0.f; s2 = 0.f;
#pragma unroll
  for (int hh = 0; hh < 8; ++hh)
#pragma unroll
    for (int t = 3; t < 7; ++t) {
      const int b = (hh * 7 + t) * 4;
      s += p[b] + p[b + 2]; s2 += p[b + 1] + p[b + 3];
    }
  mean = s * (1.f / 4096.f);
  ghms[r*4+2] = mean;
  ghms[r*4+3] = rsqrtf(s2 * (1.f / 4096.f) - mean * mean + EPSF);
}

// ---------------- MFMA GEMM: C = A @ W + bias, 128x128 tile ----------------
// B: pre-transposed bf16 WT[N][K].
// EPI: 2 G5 (h-LN A-stage; gating epilogue with on-the-fly LN gates + lci/rci)
//      3 G6 (f32 + residual), 4 CS (AF32, f32 store bias*64),
//      7 G12 (merged cumsum f32 + outx bf16, emits cs partials),
//      8 G34 (cs-LN A-stage, merged g/h raw bf16, emits g/h partials)
template <int EPI, bool AF32>
__global__ __launch_bounds__(256, 3) void gemm_kernel(
    const void* __restrict__ A, const void* __restrict__ A1, int lda, long stepA,
    const bf16_t* __restrict__ Wt, long stepW,
    const float* __restrict__ bias, int stepBias,
    const float* __restrict__ bias2,
    bf16_t* __restrict__ C, int ldc, long stepC,
    bf16_t* __restrict__ Cb2,
    float* __restrict__ Cf,
    int K, int ntph,
    const bf16_t* __restrict__ gateg,
    const float* __restrict__ resid, int sub0,
    float* __restrict__ part,
    const float* __restrict__ rs1, const float* __restrict__ rs2,
    const float* __restrict__ csq,
    const float* __restrict__ w_l, const float* __restrict__ b_l,
    const float* __restrict__ w_r, const float* __restrict__ b_r,
    const float* __restrict__ w_f, const float* __restrict__ b_f,
    const float* __restrict__ w_gg, const float* __restrict__ b_gg) {
  const int tid = threadIdx.x;
  const int lane = tid & 63, wave = tid >> 6;
  const int quad = lane >> 4, lmn = lane & 15;
  const int wm = wave >> 1, wn = wave & 1;
  const int bx = blockIdx.x;
  const int h = blockIdx.y / ntph, nt = blockIdx.y % ntph;
  const int col0 = nt * 128;
  const long row0 = (long)bx * 128;

  const bf16_t* Wtb = Wt + (long)h * stepW;
  C += (long)h * stepC;
  bias += (long)h * stepBias;

  // [128 rows][64 k] bf16 tiles, XOR-swizzled in 16B units:
  // element (row, k) lives at physical unit row*8 + ((k>>3) ^ (row&7)).
  __shared__ __align__(16) bf16_t As[128 * 64];
  __shared__ __align__(16) bf16_t Bs[128 * 64];
  __shared__ float wsum[(EPI == 7) ? 2 : 1][(EPI == 7) ? 128 : 1];

  f32x4 acc[4][4] = {};

  // register tile loader (A + B), both end as bf16x8 per j
  auto load_tile = [&](int k0, bf16x8* va, bf16x8* vb) {
#pragma unroll
    for (int j = 0; j < 4; ++j) {
      const int p = j * 256 + tid;          // physical 16B unit
      const int r = p >> 3;
      const int u = (p & 7) ^ (r & 7);      // logical k-unit (involution)
      const long r_ = row0 + r;
      if constexpr (AF32) {
        const float* ap = (const float*)A + r_ * (long)lda + (k0 + u * 8);
        const f32x4 x0 = *(const f32x4*)ap;
        const f32x4 x1 = *(const f32x4*)(ap + 4);
        bf16x8 t;
#pragma unroll
        for (int e = 0; e < 4; ++e) { t[e] = (bf16_t)x0[e]; t[4 + e] = (bf16_t)x1[e]; }
        va[j] = t;
      } else if constexpr (EPI == 8) {
        if (k0 >= 128 && k0 < 256) {  // outx segment (bf16)
          const bf16_t* ab = (const bf16_t*)A1 + h * 128;
          va[j] = *(const bf16x8*)(ab + r_ * 1024L + ((k0 & 127) + u * 8));
        } else {                      // lcg / rcg: LN(cs) on the fly
          const bool isl = (k0 < 128);
          const int cc = h * 128 + (k0 & 127) + u * 8;       // 0..1023
          const float* cp = (const float*)A + r_ * 4096L + (isl ? cc : 2048 + cc);
          const f32x4 x0 = *(const f32x4*)cp;
          const f32x4 x1 = *(const f32x4*)(cp + 4);
          const float m = rs1[r_ * 4 + (isl ? 0 : 2)];
          const float rr = rs1[r_ * 4 + (isl ? 1 : 3)];
          const float* gp = (isl ? w_l : w_r) + cc;
          const float* bp = (isl ? b_l : b_r) + cc;
          const f32x4 g0 = *(const f32x4*)gp, g1 = *(const f32x4*)(gp + 4);
          const f32x4 q0 = *(const f32x4*)bp, q1 = *(const f32x4*)(bp + 4);
          bf16x8 t;
#pragma unroll
          for (int e = 0; e < 4; ++e) {
            t[e]     = (bf16_t)((x0[e] - m) * rr * g0[e] + q0[e]);
            t[4 + e] = (bf16_t)((x1[e] - m) * rr * g1[e] + q1[e]);
          }
          va[j] = t;
        }
      } else if constexpr (EPI == 2) {  // h_pre raw -> relu(LN(.)) on the fly
        const bf16_t* ab = (const bf16_t*)A + (long)h * stepA;
        const bf16x8 xr = *(const bf16x8*)(ab + r_ * (long)lda + (k0 + u * 8));
        const int gc = h * 512 + k0 + u * 8;
        const float m = rs2[r_ * 4 + 2], rr = rs2[r_ * 4 + 3];
        const f32x4 g0 = *(const f32x4*)(w_f + gc), g1 = *(const f32x4*)(w_f + gc + 4);
        const f32x4 q0 = *(const f32x4*)(b_f + gc), q1 = *(const f32x4*)(b_f + gc + 4);
        bf16x8 t;
#pragma unroll
        for (int e = 0; e < 4; ++e) {
          t[e]     = (bf16_t)fmaxf(((float)xr[e] - m) * rr * g0[e] + q0[e], 0.f);
          t[4 + e] = (bf16_t)fmaxf(((float)xr[4 + e] - m) * rr * g1[e] + q1[e], 0.f);
        }
        va[j] = t;
      } else {                          // plain bf16 A (EPI 7, 3)
        const bf16_t* ab = (const bf16_t*)A + (long)h * stepA;
        va[j] = *(const bf16x8*)(ab + r_ * (long)lda + (k0 + u * 8));
      }
    }
#pragma unroll
    for (int j = 0; j < 4; ++j) {
      const int p = j * 256 + tid;
      const int r = p >> 3;                 // n within 128-tile
      const int u = (p & 7) ^ (r & 7);
      vb[j] = *(const bf16x8*)(Wtb + (long)(col0 + r) * K + (k0 + u * 8));
    }
  };

  bf16x8 va[4], vb[4];
  load_tile(0, va, vb);

  for (int k0 = 0; k0 < K; k0 += 64) {
#pragma unroll
    for (int j = 0; j < 4; ++j) {
      const int p = j * 256 + tid;
      *(bf16x8*)(As + p * 8) = va[j];
      *(bf16x8*)(Bs + p * 8) = vb[j];
    }
    __syncthreads();
    if (k0 + 64 < K) load_tile(k0 + 64, va, vb);
#pragma unroll
    for (int ks = 0; ks < 2; ++ks) {
      bf16x8 af[4], bfr[4];
#pragma unroll
      for (int t4 = 0; t4 < 4; ++t4) {
        const int m = wm * 64 + t4 * 16 + lmn;
        af[t4] = *(const bf16x8*)(As + (m * 8 + ((ks * 4 + quad) ^ (m & 7))) * 8);
        const int n = wn * 64 + t4 * 16 + lmn;
        bfr[t4] = *(const bf16x8*)(Bs + (n * 8 + ((ks * 4 + quad) ^ (n & 7))) * 8);
      }
#pragma unroll
      for (int im = 0; im < 4; ++im)
#pragma unroll
        for (int in = 0; in < 4; ++in)
          acc[im][in] =
              __builtin_amdgcn_mfma_f32_16x16x32_bf16(af[im], bfr[in], acc[im][in], 0, 0, 0);
    }
    __syncthreads();
  }

  // Epilogue. C/D layout: col = lane&15, row = quad*4 + reg.
  if constexpr (EPI == 7) {
    if (col0 >= 4096) {
      // outx part: bf16 store, stride 1024 (no partials)
      const int cx = col0 - 4096;
      float bvv[4];
#pragma unroll
      for (int in_ = 0; in_ < 4; ++in_)
        bvv[in_] = bias2[cx + wn * 64 + in_ * 16 + lmn];
#pragma unroll
      for (int im = 0; im < 4; ++im)
#pragma unroll
        for (int i = 0; i < 4; ++i) {
          const long r = row0 + wm * 64 + im * 16 + quad * 4 + i;
          bf16_t* dst = C + r * 1024L + cx + wn * 64 + lmn;
#pragma unroll
          for (int in_ = 0; in_ < 4; ++in_)
            dst[in_ * 16] = (bf16_t)(acc[im][in_][i] + bvv[in_]);
        }
      return;
    }
    // fused subchunk cumsum: block = one 128-row subchunk x 128 channels.
    const int sub = sub0 + bx;
    const bool fw = (col0 < 2048);
    float s64v[4];
#pragma unroll
    for (int in_ = 0; in_ < 4; ++in_) {
      const int cloc = wn * 64 + in_ * 16 + lmn;
      const int cg = col0 + cloc;
      const float bv = bias[cg];
      float v[4][4], pre[4][4], s4[4];
#pragma unroll
      for (int im = 0; im < 4; ++im) {
#pragma unroll
        for (int i = 0; i < 4; ++i) v[im][i] = acc[im][in_][i] + bv;
        if (fw) {
          pre[im][0] = v[im][0];
#pragma unroll
          for (int i = 1; i < 4; ++i) pre[im][i] = pre[im][i - 1] + v[im][i];
          s4[im] = pre[im][3];
        } else {
          pre[im][3] = v[im][3];
#pragma unroll
          for (int i = 2; i >= 0; --i) pre[im][i] = pre[im][i + 1] + v[im][i];
          s4[im] = pre[im][0];
        }
      }
      float eq[4], s16[4];
#pragma unroll
      for (int im = 0; im < 4; ++im) {
        float e = 0.f, tot = 0.f;
#pragma unroll
        for (int qq = 0; qq < 4; ++qq) {
          const float t = __shfl(s4[im], qq * 16 + lmn);
          tot += t;
          if (fw ? (qq < quad) : (qq > quad)) e += t;
        }
        eq[im] = e;
        s16[im] = tot;
      }
      float ei[4];
      if (fw) {
        ei[0] = 0.f;
#pragma unroll
        for (int im = 1; im < 4; ++im) ei[im] = ei[im - 1] + s16[im - 1];
      } else {
        ei[3] = 0.f;
#pragma unroll
        for (int im = 2; im >= 0; --im) ei[im] = ei[im + 1] + s16[im + 1];
      }
      s64v[in_] = s16[0] + s16[1] + s16[2] + s16[3];
      const float ofv = resid[(long)sub * 4096 + cg];
#pragma unroll
      for (int im = 0; im < 4; ++im)
#pragma unroll
        for (int i = 0; i < 4; ++i)
          acc[im][in_][i] = ofv + ei[im] + eq[im] + pre[im][i];
    }
    if (quad == 0) {
#pragma unroll
      for (int in_ = 0; in_ < 4; ++in_)
        wsum[wm][wn * 64 + in_ * 16 + lmn] = s64v[in_];
    }
    __syncthreads();
    float basev[4];
#pragma unroll
    for (int in_ = 0; in_ < 4; ++in_) {
      const int cloc = wn * 64 + in_ * 16 + lmn;
      basev[in_] = fw ? (wm == 1 ? wsum[0][cloc] : 0.f)
                      : (wm == 0 ? wsum[1][cloc] : 0.f);
    }
#pragma unroll
    for (int im = 0; im < 4; ++im)
#pragma unroll
      for (int i = 0; i < 4; ++i) {
        const int rl = wm * 64 + im * 16 + quad * 4 + i;
        const long r = row0 + rl;
        float* dst = Cf + r * (long)ldc + col0 + wn * 64 + lmn;
        float s = 0.f, s2 = 0.f;
#pragma unroll
        for (int in_ = 0; in_ < 4; ++in_) {
          const float v = acc[im][in_][i] + basev[in_];
          dst[in_ * 16] = v;
          s += v; s2 += v * v;
        }
#pragma unroll
        for (int m2 = 1; m2 < 16; m2 <<= 1) {
          s += __shfl_xor(s, m2); s2 += __shfl_xor(s2, m2);
        }
        if (lmn == 0) {
          float* pp = part + (r * 32L + nt) * 4 + wn * 2;
          pp[0] = s; pp[1] = s2;
        }
      }
    return;
  }

  if constexpr (EPI == 8) {
    // merged g/h (raw): cl < 384 -> C (g_pre), else -> Cb2 (h_pre); + partials
    // partials indexed by (r, h, nt, wn) — h MUST be included (R13 bug).
    float bvv[4];
    bool isgA[4];
#pragma unroll
    for (int in_ = 0; in_ < 4; ++in_) {
      const int clb = col0 + wn * 64 + in_ * 16;
      const int cl = clb + lmn;
      isgA[in_] = clb < 384;
      bvv[in_] = isgA[in_] ? bias[cl] : bias2[h * 512 + cl - 384];
    }
#pragma unroll
    for (int im = 0; im < 4; ++im)
#pragma unroll
      for (int i = 0; i < 4; ++i) {
        const int rl = wm * 64 + im * 16 + quad * 4 + i;
        const long r = row0 + rl;
        float s = 0.f, s2 = 0.f;
#pragma unroll
        for (int in_ = 0; in_ < 4; ++in_) {
          const int cl = col0 + wn * 64 + in_ * 16 + lmn;
          const float v = acc[im][in_][i] + bvv[in_];
          if (isgA[in_]) C[r * 3072L + cl] = (bf16_t)v;  // C pre-offset by h*384
          else           Cb2[r * 4096L + h * 512 + (cl - 384)] = (bf16_t)v;
          s += v; s2 += v * v;
        }
#pragma unroll
        for (int m2 = 1; m2 < 16; m2 <<= 1) {
          s += __shfl_xor(s, m2); s2 += __shfl_xor(s2, m2);
        }
        if (lmn == 0) {
          float* pp = part + (r * 56L + h * 7 + nt) * 4 + wn * 2;
          pp[0] = s; pp[1] = s2;
        }
      }
    return;
  }

  if constexpr (EPI == 2) {
    // gating epilogue: gates = sigmoid(LN(g_pre raw)); lci/rci = relu(LN(cs))
    float bvv[4];
#pragma unroll
    for (int in_ = 0; in_ < 4; ++in_)
      bvv[in_] = bias[wn * 64 + in_ * 16 + lmn];
#pragma unroll
    for (int im = 0; im < 4; ++im)
#pragma unroll
      for (int i = 0; i < 4; ++i) {
        const int rl = wm * 64 + im * 16 + quad * 4 + i;
        const long r = row0 + rl;
        const float gm = rs2[r * 4 + 0], gr = rs2[r * 4 + 1];
        const float lm = rs1[r * 4 + 0], lr = rs1[r * 4 + 1];
        const float rm = rs1[r * 4 + 2], rrv = rs1[r * 4 + 3];
        bf16_t* dst = C + r * 1024L + wn * 64 + lmn;  // C pre-offset by h*128
        const bf16_t* gg = gateg + r * 3072L + h * 384 + wn * 64 + lmn;
        const float* csr = csq + r * 4096L;
#pragma unroll
        for (int in_ = 0; in_ < 4; ++in_) {
          const int cloc = wn * 64 + in_ * 16 + lmn;
          const int gch = h * 384 + cloc;
          const float x = acc[im][in_][i] + bvv[in_];
          const float y0 = ((float)gg[in_ * 16] - gm) * gr * w_gg[gch] + b_gg[gch];
          const float y1 = ((float)gg[in_ * 16 + 128] - gm) * gr * w_gg[gch + 128] + b_gg[gch + 128];
          const float y2 = ((float)gg[in_ * 16 + 256] - gm) * gr * w_gg[gch + 256] + b_gg[gch + 256];
          const float gv0 = 1.f / (1.f + __expf(-y0));
          const float gv1 = 1.f / (1.f + __expf(-y1));
          const float gv2 = 1.f / (1.f + __expf(-y2));
          const int cL = 1024 + h * 128 + cloc;  // lci/rci channel index
          const float lv = fmaxf((csr[cL] - lm) * lr * w_l[cL] + b_l[cL], 0.f);
          const float rv = fmaxf((csr[2048 + cL] - rm) * rrv * w_r[cL] + b_r[cL], 0.f);
          dst[in_ * 16] = (bf16_t)(lv * gv0 + gv1 * x + rv * gv2);
        }
      }
    return;
  }

  // EPI 3 / 4
  {
    float bvv[4];
#pragma unroll
    for (int in_ = 0; in_ < 4; ++in_)
      bvv[in_] = bias[col0 + wn * 64 + in_ * 16 + lmn];
#pragma unroll
    for (int im = 0; im < 4; ++im)
#pragma unroll
      for (int i = 0; i < 4; ++i) {
        const long r = row0 + wm * 64 + im * 16 + quad * 4 + i;
        if constexpr (EPI == 4) {
          float* dst = Cf + r * (long)ldc + col0 + wn * 64 + lmn;
#pragma unroll
          for (int in_ = 0; in_ < 4; ++in_)
            dst[in_ * 16] = acc[im][in_][i] + 64.f * bvv[in_];
        } else {  // EPI == 3
          float* dst = Cf + r * (long)ldc + col0 + wn * 64 + lmn;
          const float* rs = resid + r * (long)ldc + col0 + wn * 64 + lmn;
#pragma unroll
          for (int in_ = 0; in_ < 4; ++in_)
            dst[in_ * 16] = acc[im][in_][i] + bvv[in_] + rs[in_ * 16];
        }
      }
  }
}

// -------- exclusive chunk-offset scan over 64-row units -> offs[128][4096] --------
__global__ __launch_bounds__(256) void scan_offs_kernel(
    const float* __restrict__ cp_, float* __restrict__ offs) {
  const int t = blockIdx.x * 256 + threadIdx.x;
  const int b = t >> 12, ch = t & 4095;
  const float* cp = cp_ + (long)b * 64 * 4096 + ch;
  float* op = offs + (long)b * 32 * 4096 + ch;
  float run = 0.f;
  if (ch < 2048) {
    for (int u = 0; u < 64; ++u) {
      if (!(u & 1)) op[(long)(u >> 1) * 4096] = run;
      run += cp[(long)u * 4096];
    }
  } else {
    for (int u = 63; u >= 0; --u) {
      if (u & 1) op[(long)(u >> 1) * 4096] = run;
      run += cp[(long)u * 4096];
    }
  }
}

// ---------------- launch ----------------
extern "C" void kernel_launch(void* const* d_in, const int* in_sizes, int n_in,
                              void* d_out, int out_size, void* d_ws, size_t ws_size,
                              hipStream_t stream) {
  (void)in_sizes; (void)n_in; (void)out_size;
  const float* inputs = (const float*)d_in[0];
  const float* W_csum = (const float*)d_in[2];
  const float* b_csum = (const float*)d_in[3];
  const float* W_x = (const float*)d_in[4];
  const float* b_x = (const float*)d_in[5];
  const float* g_l = (const float*)d_in[6];
  const float* be_l = (const float*)d_in[7];
  const float* g_r = (const float*)d_in[8];
  const float* be_r = (const float*)d_in[9];
  const float* g_g = (const float*)d_in[10];
  const float* be_g = (const float*)d_in[11];
  const float* g_f = (const float*)d_in[12];
  const float* be_f = (const float*)d_in[13];
  const float* W_g = (const float*)d_in[14];
  const float* b_g = (const float*)d_in[15];
  const float* W_f1 = (const float*)d_in[16];
  const float* b_f1 = (const float*)d_in[17];
  const float* W_f2 = (const float*)d_in[18];
  const float* b_f2 = (const float*)d_in[19];
  const float* W_o = (const float*)d_in[20];
  const float* b_o = (const float*)d_in[21];
  float* out = (float*)d_out;

  // fixed ~57.3MB; per-R: cs 16384 + outx 2048 + g_pre 6144 + h_pre 8192 +
  //   pcs 512 + pgh 896 + lrms 16 + ghms 16 = 34208 B/row
  const size_t fixedBytes = 60030976UL + 131072UL;
  int R = 128;
  for (int r = 16384; r >= 128; r >>= 1) {
    if (fixedBytes + (size_t)r * 34208UL <= ws_size) { R = r; break; }
  }
  const int CN = 16384 / R;

  char* ws = (char*)d_ws;
  size_t off = 0;
  auto alloc = [&](size_t bytes) -> char* {
    off = (off + 255) & ~(size_t)255;
    char* p = ws + off;
    off += bytes;
    return p;
  };
  float* colsum_p = (float*)alloc(256UL * 4096 * 4);
  float* offs = (float*)alloc(128UL * 4096 * 4);
  float* Srow_p = (float*)alloc(256UL * 1024 * 4);
  bf16_t* WTcsum = (bf16_t*)alloc(4096UL * 1024 * 2);  // WTx must follow
  bf16_t* WTx = (bf16_t*)alloc(1024UL * 1024 * 2);     // adjacent (256-mult sizes)
  bf16_t* WTgf = (bf16_t*)alloc(8UL * 896 * 384 * 2);  // per-head [g(384)|f1(512)]
  bf16_t* WTf2 = (bf16_t*)alloc(8UL * 128 * 512 * 2);
  bf16_t* WTo = (bf16_t*)alloc(1024UL * 1024 * 2);
  bf16_t* inb = (bf16_t*)alloc(16384UL * 1024 * 2);
  float* cs_chunk = (float*)alloc((size_t)R * 16384);
  bf16_t* outx = (bf16_t*)alloc((size_t)R * 1024 * 2);
  bf16_t* g_pre = (bf16_t*)alloc((size_t)R * 3072 * 2);
  bf16_t* h_pre = (bf16_t*)alloc((size_t)R * 4096 * 2);
  float* pcs = (float*)alloc((size_t)R * 128 * 4);
  float* pgh = (float*)alloc((size_t)R * 224 * 4);
  float* lrms = (float*)alloc((size_t)R * 16);
  float* ghms = (float*)alloc((size_t)R * 16);
  bf16_t* cell_o = outx;  // outx dead after G34

  // P0: weight conversions (bf16 [N][K])
  wtrans_kernel<<<dim3(64, 16, 1), 256, 0, stream>>>(W_csum, WTcsum, 1024, 4096, 0);
  wtrans_kernel<<<dim3(16, 16, 1), 256, 0, stream>>>(W_x, WTx, 1024, 1024, 0);
  wtrans_kernel<<<dim3(6, 6, 8), 256, 0, stream>>>(W_g, WTgf, 384, 384,
                                                   (long)896 * 384);
  wtrans_kernel<<<dim3(8, 6, 8), 256, 0, stream>>>(W_f1, WTgf + 384 * 384, 384, 512,
                                                   (long)896 * 384);
  wtrans_kernel<<<dim3(2, 8, 8), 256, 0, stream>>>(W_f2, WTf2, 512, 128,
                                                   (long)128 * 512);
  wtrans_kernel<<<dim3(16, 16, 1), 256, 0, stream>>>(W_o, WTo, 1024, 1024, 0);

  // RS (+ inputs->bf16) + CS + S1
  rowsum_cvt_kernel<<<dim3(2, 128), 256, 0, stream>>>(inputs, Srow_p, inb);
  gemm_kernel<4, true><<<dim3(2, 32), 256, 0, stream>>>(
      Srow_p, nullptr, 1024, 0, WTcsum, 0, b_csum, 0, nullptr,
      nullptr, 4096, 0, nullptr, colsum_p, 1024, 32,
      nullptr, nullptr, 0, nullptr, nullptr, nullptr, nullptr,
      nullptr, nullptr, nullptr, nullptr, nullptr, nullptr, nullptr, nullptr);
  scan_offs_kernel<<<64, 256, 0, stream>>>(colsum_p, offs);

  const int statsGrid = (R + 255) / 256;
  for (int c = 0; c < CN; ++c) {
    const long r0 = (long)c * R;
    const float* in_c = inputs + r0 * 1024;
    const bf16_t* inb_c = inb + r0 * 1024;

    // G12: cs_chunk(f32) = cumsum(in @ W_csum + b) + offs ; outx ; cs partials
    gemm_kernel<7, false><<<dim3(R / 128, 40), 256, 0, stream>>>(
        inb_c, nullptr, 1024, 0, WTcsum, 0, b_csum, 0, b_x,
        outx, 4096, 0, nullptr, cs_chunk, 1024, 40,
        nullptr, offs, (int)(r0 / 128), pcs,
        nullptr, nullptr, nullptr,
        nullptr, nullptr, nullptr, nullptr, nullptr, nullptr, nullptr, nullptr);

    ln_stats_cs_kernel<<<statsGrid, 256, 0, stream>>>(pcs, lrms, R);

    // G34: [LN(lc)|outx|LN(rc)] @ {W_g,W_f1} -> g_pre,h_pre raw ; g/h partials
    gemm_kernel<8, false><<<dim3(R / 128, 56), 256, 0, stream>>>(
        cs_chunk, outx, 0, 0, WTgf, (long)896 * 384, b_g, 384, b_f1,
        g_pre, 0, 384, h_pre, nullptr, 384, 7,
        nullptr, nullptr, 0, pgh,
        lrms, nullptr, nullptr,
        g_l, be_l, g_r, be_r, nullptr, nullptr, nullptr, nullptr);

    ln_stats_gh_kernel<<<statsGrid, 256, 0, stream>>>(pgh, ghms, R);

    // G5: x = relu(LN(h)) @ W_f2 + b_f2, gated with sig(LN(g)) + LN(cs) -> cell_o
    gemm_kernel<2, false><<<dim3(R / 128, 8), 256, 0, stream>>>(
        h_pre, nullptr, 4096, 512, WTf2, (long)128 * 512, b_f2, 128, nullptr,
        cell_o, 1024, 128, nullptr, nullptr, 512, 1,
        g_pre, nullptr, 0, nullptr,
        lrms, ghms, cs_chunk,
        g_l, be_l, g_r, be_r, g_f, be_f, g_g, be_g);

    // G6: out(f32) = cell_o @ W_o + b_o + inputs_c
    gemm_kernel<3, false><<<dim3(R / 128, 8), 256, 0, stream>>>(
        cell_o, nullptr, 1024, 0, WTo, 0, b_o, 0, nullptr,
        nullptr, 1024, 0, nullptr, out + r0 * 1024, 1024, 8,
        nullptr, in_c, 0, nullptr,
        nullptr, nullptr, nullptr,
        nullptr, nullptr, nullptr, nullptr, nullptr, nullptr, nullptr, nullptr);
  }
}

// Round 9
// 1080.041 us; speedup vs baseline: 1.0681x; 1.0681x over previous
//
#include <hip/hip_runtime.h>
#include <cstdint>

// EncoderLayer_52192442581853 — MI355X (gfx950)
// Dtype model: inputs/weights/output are ALL f32 on device. Internal compute:
// bf16 MFMA with f32 accumulation (threshold = 2% * max|ref| = 0.1175).
//
// Round 15 = R12 (1031us best) + surgical ln_gh elimination ONLY:
//  - R14 lesson: LN fused into an A-stage is free only when the consumer reads
//    each element ONCE. G34 re-stages A ntph=7 times (regression); G5 reads
//    h_pre/g_pre exactly once -> fuse there.
//  - G34 epilogue (unchanged staging) emits per-(row,head,tile,wave) partial
//    (sum,sumsq) -> pgh[R][8][7][2][2] (head-indexed: R13's race fixed).
//  - ln_stats_gh (R threads) -> ghms[R][4] = {g mean,rstd, h mean,rstd}.
//  - G5 A-stage: relu(LN(h_pre)) on the fly; G5 epilogue: sigmoid(LN(g_pre))
//    gates. lci/rci still from ln_cell (as R12). ln_gh DELETED (~470MB saved).
//
// Pipeline:
//   P0:  WT_* = bf16(W_*^T)
//   RS:  Srow_p 64-row sums; in_bf16 = bf16(inputs)
//   CS:  colsum_p = Srow_p @ W_csum + 64*b (EPI=4) ; S1: offs exclusive scan
//   per chunk:
//     G12: cs_chunk(f32) = cumsum(in @ W_csum + b) + offs ; outx = in @ W_x + b
//     L1:  LN(2048) lc/rc -> lcg, rcg, lci(relu), rci(relu)  (bf16)
//     G34: g_pre,h_pre(raw) = [lcg|outx|rcg] @ {W_g,W_f1} + b ; g/h partials
//     SG:  stats_gh -> ghms
//     G5:  x = relu(LN(h)) @ W_f2 + b_f2 ; gates=sig(LN(g)) ; cell_o
//     G6:  out(F32) = cell_o @ W_o + b_o + inputs_c(f32)

typedef __bf16 bf16_t;
using bf16x8 = __attribute__((ext_vector_type(8))) __bf16;
using bf16x4 = __attribute__((ext_vector_type(4))) __bf16;
using f32x4  = __attribute__((ext_vector_type(4))) float;

#define EPSF 1e-6f

// ---------------- weight transpose: f32 [K][N] -> bf16 [N][K] ----------------
__global__ __launch_bounds__(256) void wtrans_kernel(
    const float* __restrict__ W, bf16_t* __restrict__ WT, int K, int N,
    long outSliceStride) {
  __shared__ float tile[64][65];
  const long slice = (long)K * N;
  const float* Wp = W + (long)blockIdx.z * slice;
  bf16_t* Tp = WT + (long)blockIdx.z * outSliceStride;
  const int n0 = blockIdx.x * 64, k0 = blockIdx.y * 64;
  const int c = threadIdx.x & 63, r0 = threadIdx.x >> 6;
#pragma unroll
  for (int i = 0; i < 16; ++i)
    tile[i * 4 + r0][c] = Wp[(long)(k0 + i * 4 + r0) * N + (n0 + c)];
  __syncthreads();
#pragma unroll
  for (int i = 0; i < 16; ++i)
    Tp[(long)(n0 + i * 4 + r0) * K + (k0 + c)] = (bf16_t)tile[c][i * 4 + r0];
}

// -------- rowsum + cvt: Srow_p[sub*2+half][k] = sum over 64 rows; inb = bf16(in) --------
__global__ __launch_bounds__(256) void rowsum_cvt_kernel(
    const float* __restrict__ in, float* __restrict__ S, bf16_t* __restrict__ ob) {
  const int k = threadIdx.x * 4;
  const int half = blockIdx.x;
  const int sub = blockIdx.y;
  const long rbase = (long)sub * 128 + (long)half * 64;
  const float* p = in + rbase * 1024 + k;
  bf16_t* q = ob + rbase * 1024 + k;
  f32x4 s = {0.f, 0.f, 0.f, 0.f};
#pragma unroll 4
  for (int r = 0; r < 64; ++r) {
    const f32x4 v = *(const f32x4*)(p + (long)r * 1024);
    s += v;
    bf16x4 o;
#pragma unroll
    for (int j = 0; j < 4; ++j) o[j] = (bf16_t)v[j];
    *(bf16x4*)(q + (long)r * 1024) = o;
  }
  *(f32x4*)(S + ((long)sub * 2 + half) * 1024 + k) = s;
}

// -------- stats: reduce g/h partials -> per-row (mean, rstd) --------
__global__ __launch_bounds__(256) void ln_stats_gh_kernel(
    const float* __restrict__ pgh, float* __restrict__ ghms, int Rtot) {
  const int r = blockIdx.x * 256 + threadIdx.x;
  if (r >= Rtot) return;
  const float* p = pgh + (long)r * 224;  // [8 h][7 tiles][2 wn][2]
  float s = 0.f, s2 = 0.f;
#pragma unroll
  for (int hh = 0; hh < 8; ++hh)
#pragma unroll
    for (int t = 0; t < 3; ++t) {
      const int b = (hh * 7 + t) * 4;
      s += p[b] + p[b + 2]; s2 += p[b + 1] + p[b + 3];
    }
  float mean = s * (1.f / 3072.f);
  ghms[r*4+0] = mean;
  ghms[r*4+1] = rsqrtf(s2 * (1.f / 3072.f) - mean * mean + EPSF);
  s = 0.f; s2 = 0.f;
#pragma unroll
  for (int hh = 0; hh < 8; ++hh)
#pragma unroll
    for (int t = 3; t < 7; ++t) {
      const int b = (hh * 7 + t) * 4;
      s += p[b] + p[b + 2]; s2 += p[b + 1] + p[b + 3];
    }
  mean = s * (1.f / 4096.f);
  ghms[r*4+2] = mean;
  ghms[r*4+3] = rsqrtf(s2 * (1.f / 4096.f) - mean * mean + EPSF);
}

// ---------------- MFMA GEMM: C = A @ W + bias, 128x128 tile ----------------
// B: pre-transposed bf16 WT[N][K]. SEG3: A = three bf16 [rows][1024] buffers.
// EPI: 2 G5 (h-LN A-stage; gating epilogue with LN+sigmoid gates, lci/rci bufs)
//      3 G6 (f32 + residual), 4 CS (AF32, f32 store bias*64),
//      7 G12 (merged cumsum f32 + outx bf16), 8 G34 (g/h raw bf16 + partials)
template <int EPI, bool SEG3, bool AF32>
__global__ __launch_bounds__(256, 3) void gemm_kernel(
    const void* __restrict__ A, const void* __restrict__ A1,
    const void* __restrict__ A2, int lda, long stepA,
    const bf16_t* __restrict__ Wt, long stepW,
    const float* __restrict__ bias, int stepBias,
    const float* __restrict__ bias2,
    bf16_t* __restrict__ C, int ldc, long stepC,
    bf16_t* __restrict__ Cb2,
    float* __restrict__ Cf,
    int K, int ntph,
    const bf16_t* __restrict__ gateg,
    const bf16_t* __restrict__ lcib,
    const bf16_t* __restrict__ rcib,
    const float* __restrict__ resid, int sub0,
    float* __restrict__ part,
    const float* __restrict__ ghms,
    const float* __restrict__ w_f, const float* __restrict__ b_f,
    const float* __restrict__ w_gg, const float* __restrict__ b_gg) {
  const int tid = threadIdx.x;
  const int lane = tid & 63, wave = tid >> 6;
  const int quad = lane >> 4, lmn = lane & 15;
  const int wm = wave >> 1, wn = wave & 1;
  const int bx = blockIdx.x;
  const int h = blockIdx.y / ntph, nt = blockIdx.y % ntph;
  const int col0 = nt * 128;
  const long row0 = (long)bx * 128;

  const bf16_t* Wtb = Wt + (long)h * stepW;
  C += (long)h * stepC;
  bias += (long)h * stepBias;

  // Unpadded [128 rows][64 k] bf16 tiles, XOR-swizzled in 16B units:
  // element (row, k) lives at physical unit row*8 + ((k>>3) ^ (row&7)).
  __shared__ __align__(16) bf16_t As[128 * 64];
  __shared__ __align__(16) bf16_t Bs[128 * 64];
  __shared__ float wsum[(EPI == 7) ? 2 : 1][(EPI == 7) ? 128 : 1];

  f32x4 acc[4][4] = {};

  // register tile loader (A + B), both end as bf16x8 per j
  auto load_tile = [&](int k0, bf16x8* va, bf16x8* vb) {
#pragma unroll
    for (int j = 0; j < 4; ++j) {
      const int p = j * 256 + tid;          // physical 16B unit
      const int r = p >> 3;
      const int u = (p & 7) ^ (r & 7);      // logical k-unit (involution)
      const long r_ = row0 + r;
      if constexpr (AF32) {
        const float* ap = (const float*)A + r_ * (long)lda + (k0 + u * 8);
        const f32x4 x0 = *(const f32x4*)ap;
        const f32x4 x1 = *(const f32x4*)(ap + 4);
        bf16x8 t;
#pragma unroll
        for (int e = 0; e < 4; ++e) { t[e] = (bf16_t)x0[e]; t[4 + e] = (bf16_t)x1[e]; }
        va[j] = t;
      } else if constexpr (SEG3) {
        const bf16_t* ab =
            (const bf16_t*)(k0 < 128 ? A : (k0 < 256 ? A1 : A2)) + h * 128;
        va[j] = *(const bf16x8*)(ab + r_ * 1024L + ((k0 & 127) + u * 8));
      } else if constexpr (EPI == 2) {
        // h_pre raw -> relu(LN(.)) on the fly (each element read exactly once)
        const bf16_t* ab = (const bf16_t*)A + (long)h * stepA;
        const bf16x8 xr = *(const bf16x8*)(ab + r_ * (long)lda + (k0 + u * 8));
        const int gc = h * 512 + k0 + u * 8;
        const float m = ghms[r_ * 4 + 2], rr = ghms[r_ * 4 + 3];
        const f32x4 g0 = *(const f32x4*)(w_f + gc), g1 = *(const f32x4*)(w_f + gc + 4);
        const f32x4 q0 = *(const f32x4*)(b_f + gc), q1 = *(const f32x4*)(b_f + gc + 4);
        bf16x8 t;
#pragma unroll
        for (int e = 0; e < 4; ++e) {
          t[e]     = (bf16_t)fmaxf(((float)xr[e] - m) * rr * g0[e] + q0[e], 0.f);
          t[4 + e] = (bf16_t)fmaxf(((float)xr[4 + e] - m) * rr * g1[e] + q1[e], 0.f);
        }
        va[j] = t;
      } else {
        const bf16_t* ab = (const bf16_t*)A + (long)h * stepA;
        va[j] = *(const bf16x8*)(ab + r_ * (long)lda + (k0 + u * 8));
      }
    }
#pragma unroll
    for (int j = 0; j < 4; ++j) {
      const int p = j * 256 + tid;
      const int r = p >> 3;                 // n within 128-tile
      const int u = (p & 7) ^ (r & 7);
      vb[j] = *(const bf16x8*)(Wtb + (long)(col0 + r) * K + (k0 + u * 8));
    }
  };

  bf16x8 va[4], vb[4];
  load_tile(0, va, vb);

  for (int k0 = 0; k0 < K; k0 += 64) {
#pragma unroll
    for (int j = 0; j < 4; ++j) {
      const int p = j * 256 + tid;
      *(bf16x8*)(As + p * 8) = va[j];
      *(bf16x8*)(Bs + p * 8) = vb[j];
    }
    __syncthreads();
    // prefetch next tile's registers; latency hides under the MFMAs below
    if (k0 + 64 < K) load_tile(k0 + 64, va, vb);
#pragma unroll
    for (int ks = 0; ks < 2; ++ks) {
      bf16x8 af[4], bfr[4];
#pragma unroll
      for (int t4 = 0; t4 < 4; ++t4) {
        const int m = wm * 64 + t4 * 16 + lmn;
        af[t4] = *(const bf16x8*)(As + (m * 8 + ((ks * 4 + quad) ^ (m & 7))) * 8);
        const int n = wn * 64 + t4 * 16 + lmn;
        bfr[t4] = *(const bf16x8*)(Bs + (n * 8 + ((ks * 4 + quad) ^ (n & 7))) * 8);
      }
#pragma unroll
      for (int im = 0; im < 4; ++im)
#pragma unroll
        for (int in = 0; in < 4; ++in)
          acc[im][in] =
              __builtin_amdgcn_mfma_f32_16x16x32_bf16(af[im], bfr[in], acc[im][in], 0, 0, 0);
    }
    __syncthreads();
  }

  // Epilogue. C/D layout: col = lane&15, row = quad*4 + reg.
  // Store loops: im,i OUTER / in_ INNER (full 64B sectors — R12 win).
  if constexpr (EPI == 7) {
    if (col0 >= 4096) {
      // outx part: bf16 store, stride 1024
      const int cx = col0 - 4096;
      float bvv[4];
#pragma unroll
      for (int in_ = 0; in_ < 4; ++in_)
        bvv[in_] = bias2[cx + wn * 64 + in_ * 16 + lmn];
#pragma unroll
      for (int im = 0; im < 4; ++im)
#pragma unroll
        for (int i = 0; i < 4; ++i) {
          const long r = row0 + wm * 64 + im * 16 + quad * 4 + i;
          bf16_t* dst = C + r * 1024L + cx + wn * 64 + lmn;
#pragma unroll
          for (int in_ = 0; in_ < 4; ++in_)
            dst[in_ * 16] = (bf16_t)(acc[im][in_][i] + bvv[in_]);
        }
      return;
    }
    // fused subchunk cumsum: block = one 128-row subchunk x 128 channels.
    const int sub = sub0 + bx;
    const bool fw = (col0 < 2048);  // uniform per block (col0 multiple of 128)
    float s64v[4];
#pragma unroll
    for (int in_ = 0; in_ < 4; ++in_) {
      const int cloc = wn * 64 + in_ * 16 + lmn;
      const int cg = col0 + cloc;
      const float bv = bias[cg];
      float v[4][4], pre[4][4], s4[4];
#pragma unroll
      for (int im = 0; im < 4; ++im) {
#pragma unroll
        for (int i = 0; i < 4; ++i) v[im][i] = acc[im][in_][i] + bv;
        if (fw) {
          pre[im][0] = v[im][0];
#pragma unroll
          for (int i = 1; i < 4; ++i) pre[im][i] = pre[im][i - 1] + v[im][i];
          s4[im] = pre[im][3];
        } else {
          pre[im][3] = v[im][3];
#pragma unroll
          for (int i = 2; i >= 0; --i) pre[im][i] = pre[im][i + 1] + v[im][i];
          s4[im] = pre[im][0];
        }
      }
      float eq[4], s16[4];
#pragma unroll
      for (int im = 0; im < 4; ++im) {
        float e = 0.f, tot = 0.f;
#pragma unroll
        for (int qq = 0; qq < 4; ++qq) {
          const float t = __shfl(s4[im], qq * 16 + lmn);
          tot += t;
          if (fw ? (qq < quad) : (qq > quad)) e += t;
        }
        eq[im] = e;
        s16[im] = tot;
      }
      float ei[4];
      if (fw) {
        ei[0] = 0.f;
#pragma unroll
        for (int im = 1; im < 4; ++im) ei[im] = ei[im - 1] + s16[im - 1];
      } else {
        ei[3] = 0.f;
#pragma unroll
        for (int im = 2; im >= 0; --im) ei[im] = ei[im + 1] + s16[im + 1];
      }
      s64v[in_] = s16[0] + s16[1] + s16[2] + s16[3];
      const float ofv = resid[(long)sub * 4096 + cg];
#pragma unroll
      for (int im = 0; im < 4; ++im)
#pragma unroll
        for (int i = 0; i < 4; ++i)
          acc[im][in_][i] = ofv + ei[im] + eq[im] + pre[im][i];
    }
    if (quad == 0) {
#pragma unroll
      for (int in_ = 0; in_ < 4; ++in_)
        wsum[wm][wn * 64 + in_ * 16 + lmn] = s64v[in_];
    }
    __syncthreads();
    float basev[4];
#pragma unroll
    for (int in_ = 0; in_ < 4; ++in_) {
      const int cloc = wn * 64 + in_ * 16 + lmn;
      basev[in_] = fw ? (wm == 1 ? wsum[0][cloc] : 0.f)
                      : (wm == 0 ? wsum[1][cloc] : 0.f);
    }
#pragma unroll
    for (int im = 0; im < 4; ++im)
#pragma unroll
      for (int i = 0; i < 4; ++i) {
        const long r = row0 + wm * 64 + im * 16 + quad * 4 + i;
        float* dst = Cf + r * (long)ldc + col0 + wn * 64 + lmn;
#pragma unroll
        for (int in_ = 0; in_ < 4; ++in_)
          dst[in_ * 16] = acc[im][in_][i] + basev[in_];
      }
    return;
  }

  if constexpr (EPI == 8) {
    // merged g/h (raw): cl < 384 -> C (g_pre), else -> Cb2 (h_pre); + partials
    // partials indexed (r, h, nt, wn) — head term essential (R13 race).
    float bvv[4];
    bool isgA[4];
#pragma unroll
    for (int in_ = 0; in_ < 4; ++in_) {
      const int clb = col0 + wn * 64 + in_ * 16;
      const int cl = clb + lmn;
      isgA[in_] = clb < 384;
      bvv[in_] = isgA[in_] ? bias[cl] : bias2[h * 512 + cl - 384];
    }
#pragma unroll
    for (int im = 0; im < 4; ++im)
#pragma unroll
      for (int i = 0; i < 4; ++i) {
        const long r = row0 + wm * 64 + im * 16 + quad * 4 + i;
        float s = 0.f, s2 = 0.f;
#pragma unroll
        for (int in_ = 0; in_ < 4; ++in_) {
          const int cl = col0 + wn * 64 + in_ * 16 + lmn;
          const float v = acc[im][in_][i] + bvv[in_];
          if (isgA[in_]) C[r * 3072L + cl] = (bf16_t)v;  // C pre-offset by h*384
          else           Cb2[r * 4096L + h * 512 + (cl - 384)] = (bf16_t)v;
          s += v; s2 += v * v;
        }
#pragma unroll
        for (int m2 = 1; m2 < 16; m2 <<= 1) {
          s += __shfl_xor(s, m2); s2 += __shfl_xor(s2, m2);
        }
        if (lmn == 0) {
          float* pp = part + (r * 56L + h * 7 + nt) * 4 + wn * 2;
          pp[0] = s; pp[1] = s2;
        }
      }
    return;
  }

  // generic epilogues (EPI 2/3/4)
  {
    float bvv[4];
#pragma unroll
    for (int in_ = 0; in_ < 4; ++in_)
      bvv[in_] = bias[col0 + wn * 64 + in_ * 16 + lmn];
#pragma unroll
    for (int im = 0; im < 4; ++im)
#pragma unroll
      for (int i = 0; i < 4; ++i) {
        const long r = row0 + wm * 64 + im * 16 + quad * 4 + i;
        if constexpr (EPI == 4) {
          float* dst = Cf + r * (long)ldc + col0 + wn * 64 + lmn;
#pragma unroll
          for (int in_ = 0; in_ < 4; ++in_)
            dst[in_ * 16] = acc[im][in_][i] + 64.f * bvv[in_];
        } else if constexpr (EPI == 3) {
          float* dst = Cf + r * (long)ldc + col0 + wn * 64 + lmn;
          const float* rs = resid + r * (long)ldc + col0 + wn * 64 + lmn;
#pragma unroll
          for (int in_ = 0; in_ < 4; ++in_)
            dst[in_ * 16] = acc[im][in_][i] + bvv[in_] + rs[in_ * 16];
        } else {  // EPI == 2 (gating) ; col0 == 0, ntph == 1
          const float gm = ghms[r * 4 + 0], gr = ghms[r * 4 + 1];
          bf16_t* dst = C + r * 1024L + wn * 64 + lmn;  // C pre-offset by h*128
          const bf16_t* gg = gateg + r * 3072L + h * 384 + wn * 64 + lmn;
          const bf16_t* lp = lcib + r * 1024 + h * 128 + wn * 64 + lmn;
          const bf16_t* rp = rcib + r * 1024 + h * 128 + wn * 64 + lmn;
#pragma unroll
          for (int in_ = 0; in_ < 4; ++in_) {
            const int cloc = wn * 64 + in_ * 16 + lmn;
            const int gch = h * 384 + cloc;
            const float v = acc[im][in_][i] + bvv[in_];
            const float y0 = ((float)gg[in_ * 16] - gm) * gr * w_gg[gch] + b_gg[gch];
            const float y1 = ((float)gg[in_ * 16 + 128] - gm) * gr * w_gg[gch + 128] + b_gg[gch + 128];
            const float y2 = ((float)gg[in_ * 16 + 256] - gm) * gr * w_gg[gch + 256] + b_gg[gch + 256];
            const float gv0 = 1.f / (1.f + __expf(-y0));
            const float gv1 = 1.f / (1.f + __expf(-y1));
            const float gv2 = 1.f / (1.f + __expf(-y2));
            const float lv = (float)lp[in_ * 16];
            const float rv = (float)rp[in_ * 16];
            dst[in_ * 16] = (bf16_t)(lv * gv0 + gv1 * v + rv * gv2);
          }
        }
      }
  }
}

// -------- exclusive chunk-offset scan over 64-row units -> offs[128][4096] --------
__global__ __launch_bounds__(256) void scan_offs_kernel(
    const float* __restrict__ cp_, float* __restrict__ offs) {
  const int t = blockIdx.x * 256 + threadIdx.x;
  const int b = t >> 12, ch = t & 4095;
  const float* cp = cp_ + (long)b * 64 * 4096 + ch;
  float* op = offs + (long)b * 32 * 4096 + ch;
  float run = 0.f;
  if (ch < 2048) {
    for (int u = 0; u < 64; ++u) {
      if (!(u & 1)) op[(long)(u >> 1) * 4096] = run;
      run += cp[(long)u * 4096];
    }
  } else {
    for (int u = 63; u >= 0; --u) {
      if (u & 1) op[(long)(u >> 1) * 4096] = run;
      run += cp[(long)u * 4096];
    }
  }
}

// ---------------- LN over lc(2048)/rc(2048) f32 -> lcg, rcg, lci, rci (bf16) ----------------
__global__ __launch_bounds__(256) void ln_cell_kernel(
    const float* __restrict__ cs,
    const float* __restrict__ g_l, const float* __restrict__ be_l,
    const float* __restrict__ g_r, const float* __restrict__ be_r,
    bf16_t* __restrict__ lcg, bf16_t* __restrict__ rcg,
    bf16_t* __restrict__ lci, bf16_t* __restrict__ rci) {
  const int token = blockIdx.x, tid = threadIdx.x;
  const int lane = tid & 63, wave = tid >> 6;
  const long tb = (long)token * 4096;
  const int c0 = tid * 16;
  float v[16];
#pragma unroll
  for (int q = 0; q < 4; ++q) {
    const f32x4 a = *(const f32x4*)(cs + tb + c0 + q * 4);
#pragma unroll
    for (int j = 0; j < 4; ++j) v[q * 4 + j] = a[j];
  }
  float s = 0.f, s2 = 0.f;
#pragma unroll
  for (int j = 0; j < 16; ++j) { s += v[j]; s2 += v[j] * v[j]; }
  for (int m = 1; m < 64; m <<= 1) { s += __shfl_xor(s, m); s2 += __shfl_xor(s2, m); }
  __shared__ float sm[4], sm2[4];
  if (lane == 0) { sm[wave] = s; sm2[wave] = s2; }
  __syncthreads();
  const int g = tid >> 7;
  const float S = sm[g * 2] + sm[g * 2 + 1];
  const float S2 = sm2[g * 2] + sm2[g * 2 + 1];
  const float mean = S * (1.f / 2048.f);
  const float rstd = rsqrtf(S2 * (1.f / 2048.f) - mean * mean + EPSF);

  const float* gp = (c0 < 2048) ? g_l : g_r;
  const float* bp = (c0 < 2048) ? be_l : be_r;
  const int cc = c0 & 2047;
  float y[16];
#pragma unroll
  for (int j = 0; j < 16; ++j)
    y[j] = (v[j] - mean) * rstd * gp[cc + j] + bp[cc + j];

  const int part = c0 >> 10;
  bf16_t* dst;
  if (part == 0)      dst = lcg + (long)token * 1024 + c0;
  else if (part == 1) dst = lci + (long)token * 1024 + (c0 - 1024);
  else if (part == 2) dst = rcg + (long)token * 1024 + (c0 - 2048);
  else                dst = rci + (long)token * 1024 + (c0 - 3072);
  if (part & 1) {
#pragma unroll
    for (int j = 0; j < 16; ++j) y[j] = fmaxf(y[j], 0.f);
  }
  bf16x8 o1, o2;
#pragma unroll
  for (int j = 0; j < 8; ++j) { o1[j] = (bf16_t)y[j]; o2[j] = (bf16_t)y[8 + j]; }
  *(bf16x8*)dst = o1;
  *(bf16x8*)(dst + 8) = o2;
}

// ---------------- launch ----------------
extern "C" void kernel_launch(void* const* d_in, const int* in_sizes, int n_in,
                              void* d_out, int out_size, void* d_ws, size_t ws_size,
                              hipStream_t stream) {
  (void)in_sizes; (void)n_in; (void)out_size;
  const float* inputs = (const float*)d_in[0];
  const float* W_csum = (const float*)d_in[2];
  const float* b_csum = (const float*)d_in[3];
  const float* W_x = (const float*)d_in[4];
  const float* b_x = (const float*)d_in[5];
  const float* g_l = (const float*)d_in[6];
  const float* be_l = (const float*)d_in[7];
  const float* g_r = (const float*)d_in[8];
  const float* be_r = (const float*)d_in[9];
  const float* g_g = (const float*)d_in[10];
  const float* be_g = (const float*)d_in[11];
  const float* g_f = (const float*)d_in[12];
  const float* be_f = (const float*)d_in[13];
  const float* W_g = (const float*)d_in[14];
  const float* b_g = (const float*)d_in[15];
  const float* W_f1 = (const float*)d_in[16];
  const float* b_f1 = (const float*)d_in[17];
  const float* W_f2 = (const float*)d_in[18];
  const float* b_f2 = (const float*)d_in[19];
  const float* W_o = (const float*)d_in[20];
  const float* b_o = (const float*)d_in[21];
  float* out = (float*)d_out;

  // fixed ~59.6MB; per-R: cs 16384 + outx 2048 + lcg/rcg/lci/rci 4*2048 +
  //   pgh 896 + ghms 16 = 27536 B/row
  const size_t fixedBytes = 59506688UL + 131072UL;
  int R = 128;
  for (int r = 16384; r >= 128; r >>= 1) {
    if (fixedBytes + (size_t)r * 27536UL <= ws_size) { R = r; break; }
  }
  const int CN = 16384 / R;

  char* ws = (char*)d_ws;
  size_t off = 0;
  auto alloc = [&](size_t bytes) -> char* {
    off = (off + 255) & ~(size_t)255;
    char* p = ws + off;
    off += bytes;
    return p;
  };
  float* colsum_p = (float*)alloc(256UL * 4096 * 4);
  float* offs = (float*)alloc(128UL * 4096 * 4);
  float* Srow_p = (float*)alloc(256UL * 1024 * 4);
  bf16_t* WTcsum = (bf16_t*)alloc(4096UL * 1024 * 2);  // WTx must follow
  bf16_t* WTx = (bf16_t*)alloc(1024UL * 1024 * 2);     // adjacent (256-mult sizes)
  bf16_t* WTgf = (bf16_t*)alloc(8UL * 896 * 384 * 2);  // per-head [g(384)|f1(512)]
  bf16_t* WTf2 = (bf16_t*)alloc(8UL * 128 * 512 * 2);
  bf16_t* WTo = (bf16_t*)alloc(1024UL * 1024 * 2);
  bf16_t* inb = (bf16_t*)alloc(16384UL * 1024 * 2);
  float* cs_chunk = (float*)alloc((size_t)R * 16384);
  bf16_t* outx = (bf16_t*)alloc((size_t)R * 1024 * 2);
  bf16_t* lcg = (bf16_t*)alloc((size_t)R * 1024 * 2);
  bf16_t* rcg = (bf16_t*)alloc((size_t)R * 1024 * 2);
  bf16_t* lci = (bf16_t*)alloc((size_t)R * 1024 * 2);
  bf16_t* rci = (bf16_t*)alloc((size_t)R * 1024 * 2);
  float* pgh = (float*)alloc((size_t)R * 224 * 4);
  float* ghms = (float*)alloc((size_t)R * 16);
  // cs_chunk is dead after G5... but G5 reads it? No: G5 reads lci/rci bufs.
  // cs_chunk dead after ln_cell; g_pre/h_pre alias it (stream-serialized).
  bf16_t* g_pre = (bf16_t*)cs_chunk;                              // R*3072 bf16
  bf16_t* h_pre = (bf16_t*)((char*)cs_chunk + (size_t)R * 6144);  // R*4096 bf16
  bf16_t* cell_o = outx;  // outx dead after G34

  // P0: weight conversions (bf16 [N][K])
  wtrans_kernel<<<dim3(64, 16, 1), 256, 0, stream>>>(W_csum, WTcsum, 1024, 4096, 0);
  wtrans_kernel<<<dim3(16, 16, 1), 256, 0, stream>>>(W_x, WTx, 1024, 1024, 0);
  wtrans_kernel<<<dim3(6, 6, 8), 256, 0, stream>>>(W_g, WTgf, 384, 384,
                                                   (long)896 * 384);
  wtrans_kernel<<<dim3(8, 6, 8), 256, 0, stream>>>(W_f1, WTgf + 384 * 384, 384, 512,
                                                   (long)896 * 384);
  wtrans_kernel<<<dim3(2, 8, 8), 256, 0, stream>>>(W_f2, WTf2, 512, 128,
                                                   (long)128 * 512);
  wtrans_kernel<<<dim3(16, 16, 1), 256, 0, stream>>>(W_o, WTo, 1024, 1024, 0);

  // RS (+ inputs->bf16) + CS + S1
  rowsum_cvt_kernel<<<dim3(2, 128), 256, 0, stream>>>(inputs, Srow_p, inb);
  gemm_kernel<4, false, true><<<dim3(2, 32), 256, 0, stream>>>(
      Srow_p, nullptr, nullptr, 1024, 0, WTcsum, 0, b_csum, 0, nullptr,
      nullptr, 4096, 0, nullptr, colsum_p, 1024, 32,
      nullptr, nullptr, nullptr, nullptr, 0,
      nullptr, nullptr, nullptr, nullptr, nullptr, nullptr);
  scan_offs_kernel<<<64, 256, 0, stream>>>(colsum_p, offs);

  const int statsGrid = (R + 255) / 256;
  for (int c = 0; c < CN; ++c) {
    const long r0 = (long)c * R;
    const float* in_c = inputs + r0 * 1024;
    const bf16_t* inb_c = inb + r0 * 1024;

    // G12: cs_chunk(f32) = cumsum(in @ W_csum + b) + offs ; outx = in @ W_x + b
    gemm_kernel<7, false, false><<<dim3(R / 128, 40), 256, 0, stream>>>(
        inb_c, nullptr, nullptr, 1024, 0, WTcsum, 0, b_csum, 0, b_x,
        outx, 4096, 0, nullptr, cs_chunk, 1024, 40,
        nullptr, nullptr, nullptr, offs, (int)(r0 / 128),
        nullptr, nullptr, nullptr, nullptr, nullptr, nullptr);

    // L1: LN(2048) x2 -> lcg, rcg, lci, rci
    ln_cell_kernel<<<R, 256, 0, stream>>>(cs_chunk, g_l, be_l, g_r, be_r,
                                          lcg, rcg, lci, rci);

    // G34: g_pre,h_pre raw = [lcg|outx|rcg] @ {W_g,W_f1} + b ; g/h partials
    // (g_pre/h_pre alias cs_chunk — cs dead after L1)
    gemm_kernel<8, true, false><<<dim3(R / 128, 56), 256, 0, stream>>>(
        lcg, outx, rcg, 1024, 0, WTgf, (long)896 * 384, b_g, 384, b_f1,
        g_pre, 3072, 384, h_pre, nullptr, 384, 7,
        nullptr, nullptr, nullptr, nullptr, 0,
        pgh, nullptr, nullptr, nullptr, nullptr, nullptr);

    ln_stats_gh_kernel<<<statsGrid, 256, 0, stream>>>(pgh, ghms, R);

    // G5: x = relu(LN(h_pre)) @ W_f2 + b_f2 ; gates = sig(LN(g_pre)) -> cell_o
    gemm_kernel<2, false, false><<<dim3(R / 128, 8), 256, 0, stream>>>(
        h_pre, nullptr, nullptr, 4096, 512, WTf2, (long)128 * 512, b_f2, 128,
        nullptr, cell_o, 1024, 128, nullptr, nullptr, 512, 1,
        g_pre, lci, rci, nullptr, 0,
        nullptr, ghms, g_f, be_f, g_g, be_g);

    // G6: out(f32) = cell_o @ W_o + b_o + inputs_c
    gemm_kernel<3, false, false><<<dim3(R / 128, 8), 256, 0, stream>>>(
        cell_o, nullptr, nullptr, 1024, 0, WTo, 0, b_o, 0, nullptr,
        nullptr, 1024, 0, nullptr, out + r0 * 1024, 1024, 8,
        nullptr, nullptr, nullptr, in_c, 0,
        nullptr, nullptr, nullptr, nullptr, nullptr, nullptr);
  }
}